// Round 3
// baseline (2721.434 us; speedup 1.0000x reference)
//
#include <hip/hip_runtime.h>
#include <string.h>

typedef unsigned short ushort_t;

#define NLAYER 3
#define MROWS 2048      // B*L = 4*512
#define DM 512
#define DFF_ 2048
#define VOCAB 32000

__device__ __forceinline__ float b2f(ushort_t u){
  union { unsigned int u; float f; } c; c.u = ((unsigned int)u) << 16; return c.f;
}
__device__ __forceinline__ ushort_t f2b(float f){
  union { float f; unsigned int u; } c; c.f = f;
  unsigned int u = c.u;
  u += 0x7FFFu + ((u >> 16) & 1u);   // RNE
  return (ushort_t)(u >> 16);
}

using bf16x8 = __attribute__((ext_vector_type(8))) short;
using f32x4  = __attribute__((ext_vector_type(4))) float;

typedef const __attribute__((address_space(1))) unsigned int* gas1_t;
typedef __attribute__((address_space(3))) unsigned int* las3_t;
__device__ __forceinline__ void gload16(const void* g, void* l){
  // async global->LDS, 16B/lane; LDS dest = wave-uniform base + lane*16
  __builtin_amdgcn_global_load_lds((gas1_t)g, (las3_t)l, 16, 0, 0);
}

// ---------------- arena layout (elems, all bf16) ----------------
#define LW  262144ull     // 512*512
#define LF  1048576ull    // 2048*512
#define PROJ_T 16384000ull
#define OFF_ENC_QKV (0ull)
#define OFF_ENC_O   (9ull*LW)
#define OFF_DEC_QKV (12ull*LW)
#define OFF_DEC_O   (21ull*LW)
#define OFF_DC_Q    (24ull*LW)
#define OFF_DC_KV   (27ull*LW)
#define OFF_DC_O    (33ull*LW)
#define OFF_EF1     (36ull*LW)
#define OFF_EF2     (36ull*LW + 3ull*LF)
#define OFF_DF1     (36ull*LW + 6ull*LF)
#define OFF_DF2     (36ull*LW + 9ull*LF)
#define OFF_PROJ    (36ull*LW + 12ull*LF)
#define ARENA_ELEMS (36ull*LW + 12ull*LF + PROJ_T)

// ---------------- dtype detect: pe[0,0]=0.0, pe[0,1]=1.0 ----------------
__global__ void detect_kernel(const unsigned* __restrict__ pe, int* flag){
  if (threadIdx.x == 0) *flag = (pe[0] != 0u) ? 1 : 0;   // 1 = bf16 storage
}

__device__ __forceinline__ float loadIn(const void* p, size_t i, int isbf){
  return isbf ? b2f(((const ushort_t*)p)[i]) : ((const float*)p)[i];
}

// ---------------- embedding + positional encoding ----------------
__global__ __launch_bounds__(256) void embed_kernel(
    const int* __restrict__ flagp, const int* __restrict__ tok,
    const void* __restrict__ emb, const void* __restrict__ pe,
    float* __restrict__ out)
{
  int isbf = *flagp;
  int row = blockIdx.x, tid = threadIdx.x;
  int t = row & 511;
  int id = tok[row];
  const float scale = 22.62741699796952f;   // sqrt(512)
  #pragma unroll
  for (int i = 0; i < 2; i++){
    int d = tid + i*256;
    float e = loadIn(emb, (size_t)id*DM + d, isbf);
    float p = loadIn(pe,  (size_t)t*DM + d, isbf);
    out[(size_t)row*DM + d] = e * scale + p;
  }
}

// ---------------- layernorm: fp32 in -> bf16 out ----------------
__global__ __launch_bounds__(256) void ln_kernel(
    const int* __restrict__ flagp, const float* __restrict__ x,
    const void* __restrict__ g, size_t goff,
    const void* __restrict__ beta, size_t boff,
    ushort_t* __restrict__ out)
{
  int isbf = *flagp;
  __shared__ float red[8];
  int row = blockIdx.x, tid = threadIdx.x;
  const float* xr = x + (size_t)row*DM;
  float v0 = xr[tid], v1 = xr[tid+256];
  float s = v0 + v1;
  #pragma unroll
  for (int off = 1; off < 64; off <<= 1) s += __shfl_xor(s, off);
  if ((tid & 63) == 0) red[tid >> 6] = s;
  __syncthreads();
  float mean = (red[0]+red[1]+red[2]+red[3]) * (1.f/512.f);
  float d0 = v0 - mean, d1 = v1 - mean;
  float sq = d0*d0 + d1*d1;
  #pragma unroll
  for (int off = 1; off < 64; off <<= 1) sq += __shfl_xor(sq, off);
  if ((tid & 63) == 0) red[4 + (tid >> 6)] = sq;
  __syncthreads();
  float var = (red[4]+red[5]+red[6]+red[7]) * (1.f/512.f);
  float rs = rsqrtf(var + 1e-5f);
  float g0 = loadIn(g, goff + tid, isbf),     g1 = loadIn(g, goff + tid + 256, isbf);
  float b0 = loadIn(beta, boff + tid, isbf),  b1 = loadIn(beta, boff + tid + 256, isbf);
  out[(size_t)row*DM + tid]       = f2b(d0*rs*g0 + b0);
  out[(size_t)row*DM + tid + 256] = f2b(d1*rs*g1 + b1);
}

// ---------------- weight staging into bf16 arena (convert fp32 / copy bf16) ----
// each block handles 2048 elems
__device__ __forceinline__ void stage_chunk(int isbf, ushort_t* __restrict__ dst,
                                            const void* __restrict__ src,
                                            size_t soff, size_t doff, int tid)
{
  size_t so = soff + (size_t)tid*8;
  size_t dofs = doff + (size_t)tid*8;
  if (isbf){
    *(uint4*)(dst + dofs) = *(const uint4*)((const ushort_t*)src + so);
  } else {
    const float* s = (const float*)src;
    float4 a = *(const float4*)(s + so);
    float4 b = *(const float4*)(s + so + 4);
    union { ushort_t u[8]; uint4 v; } pk;
    pk.u[0]=f2b(a.x); pk.u[1]=f2b(a.y); pk.u[2]=f2b(a.z); pk.u[3]=f2b(a.w);
    pk.u[4]=f2b(b.x); pk.u[5]=f2b(b.y); pk.u[6]=f2b(b.z); pk.u[7]=f2b(b.w);
    *(uint4*)(dst + dofs) = pk.v;
  }
}

// 12 attention weight tensors [3,512,512] -> fused per-layer arena layout
__global__ __launch_bounds__(256) void conv12_kernel(const int* __restrict__ flagp,
    ushort_t* __restrict__ dst,
    const void* __restrict__ s0, const void* __restrict__ s1,
    const void* __restrict__ s2, const void* __restrict__ s3,
    const void* __restrict__ s4, const void* __restrict__ s5,
    const void* __restrict__ s6, const void* __restrict__ s7,
    const void* __restrict__ s8, const void* __restrict__ s9,
    const void* __restrict__ s10, const void* __restrict__ s11)
{
  int isbf = *flagp;
  int t  = blockIdx.x / 384;          // 12 tensors x (3 layers x 128 blocks)
  int lb = blockIdx.x - t*384;
  int l  = lb >> 7;
  int blk= lb & 127;
  const void* s = t==0?s0:t==1?s1:t==2?s2:t==3?s3:t==4?s4:t==5?s5:
                  t==6?s6:t==7?s7:t==8?s8:t==9?s9:t==10?s10:s11;
  // dst base + per-layer stride (fused layouts)
  size_t base, stride;
  switch(t){
    case 0:  base = OFF_ENC_QKV;        stride = 3*LW; break;  // eWq
    case 1:  base = OFF_ENC_QKV + LW;   stride = 3*LW; break;  // eWk
    case 2:  base = OFF_ENC_QKV + 2*LW; stride = 3*LW; break;  // eWv
    case 3:  base = OFF_ENC_O;          stride = LW;   break;  // eWo
    case 4:  base = OFF_DEC_QKV;        stride = 3*LW; break;  // dsWq
    case 5:  base = OFF_DEC_QKV + LW;   stride = 3*LW; break;  // dsWk
    case 6:  base = OFF_DEC_QKV + 2*LW; stride = 3*LW; break;  // dsWv
    case 7:  base = OFF_DEC_O;          stride = LW;   break;  // dsWo
    case 8:  base = OFF_DC_Q;           stride = LW;   break;  // dcWq
    case 9:  base = OFF_DC_KV;          stride = 2*LW; break;  // dcWk
    case 10: base = OFF_DC_KV + LW;     stride = 2*LW; break;  // dcWv
    default: base = OFF_DC_O;           stride = LW;   break;  // dcWo
  }
  stage_chunk(isbf, dst, s, (size_t)l*LW + (size_t)blk*2048,
              base + (size_t)l*stride + (size_t)blk*2048, threadIdx.x);
}

// 4 FFN weight tensors [3,*,*] -> arena
__global__ __launch_bounds__(256) void conv4_kernel(const int* __restrict__ flagp,
    ushort_t* __restrict__ dst,
    const void* __restrict__ s0, const void* __restrict__ s1,
    const void* __restrict__ s2, const void* __restrict__ s3)
{
  int isbf = *flagp;
  int t  = blockIdx.x / 1536;          // 4 tensors x (3 layers x 512 blocks)
  int lb = blockIdx.x - t*1536;
  int l  = lb >> 9;
  int blk= lb & 511;
  const void* s = t==0?s0:t==1?s1:t==2?s2:s3;
  size_t base = t==0?OFF_EF1 : t==1?OFF_EF2 : t==2?OFF_DF1 : OFF_DF2;
  stage_chunk(isbf, dst, s, (size_t)l*LF + (size_t)blk*2048,
              base + (size_t)l*LF + (size_t)blk*2048, threadIdx.x);
}

// projW 32000*512 (8000 blocks)
__global__ __launch_bounds__(256) void conv1_kernel(const int* __restrict__ flagp,
    ushort_t* __restrict__ dst, const void* __restrict__ src)
{
  int isbf = *flagp;
  stage_chunk(isbf, dst, src, (size_t)blockIdx.x*2048,
              OFF_PROJ + (size_t)blockIdx.x*2048, threadIdx.x);
}

// ---------------- GEMM: C[M,N] = A[M,K](bf16) @ W[N,K]^T(arena bf16) + bias ----
// Block tile (MT*32) x (NT*32), 4 waves 2x2, each wave MT x NT 16x16 frags.
// XOR-swizzled LDS via pre-swizzled global source (write linear, read swizzled).
template<int MT, int NT>
__device__ __forceinline__ void gemm_core(
    int isbf, const ushort_t* __restrict__ A, const ushort_t* __restrict__ W,
    const void* __restrict__ b0, const void* __restrict__ b1, const void* __restrict__ b2,
    size_t boff, int segsh,
    const float* __restrict__ resid, float* __restrict__ addout,
    void* __restrict__ out, int om, int ldc, int K, int relu,
    ushort_t* As, ushort_t* Ws)
{
  constexpr int BM = MT*32, BN = NT*32;
  int tid = threadIdx.x;
  // XCD-chunked bijective swizzle (nwg always %8==0 here)
  int flat = blockIdx.y * gridDim.x + blockIdx.x;
  int nwg  = gridDim.x * gridDim.y;
  int swz = flat;
  if ((nwg & 7) == 0){ int cpx = nwg >> 3; swz = (flat & 7) * cpx + (flat >> 3); }
  int bm = swz % (int)gridDim.x;
  int bn = swz / (int)gridDim.x;

  int wave = tid >> 6, lane = tid & 63;
  int wr = wave >> 1, wc = wave & 1;
  f32x4 acc[MT][NT];
  #pragma unroll
  for (int i=0;i<MT;i++)
    #pragma unroll
    for (int j=0;j<NT;j++) acc[i][j] = (f32x4){0.f,0.f,0.f,0.f};

  // physical col-slot p of row r holds logical 16B-slot s = p ^ (r&7)
  int srow = tid >> 3;
  int scol = (((tid & 7) ^ (srow & 7)) * 8);
  const ushort_t* Ag = A + (size_t)(bm*BM + srow)*K + scol;
  const ushort_t* Wg = W + (size_t)(bn*BN + srow)*K + scol;
  ushort_t* ldsA = As + wave*512;   // wave-uniform; 1KB per wave per stage
  ushort_t* ldsW = Ws + wave*512;

  int fm = lane & 15;
  int xa = fm & 7;

  for (int k0 = 0; k0 < K; k0 += 64){
    #pragma unroll
    for (int j = 0; j < MT; j++)
      gload16(Ag + (size_t)(j*32)*K + k0, ldsA + j*2048);
    #pragma unroll
    for (int j = 0; j < NT; j++)
      gload16(Wg + (size_t)(j*32)*K + k0, ldsW + j*2048);
    __syncthreads();    // compiler drains vmcnt before s_barrier
    #pragma unroll
    for (int kk = 0; kk < 2; kk++){
      int p8 = (((lane >> 4) + kk*4) ^ xa) * 8;
      bf16x8 a[MT], b[NT];
      #pragma unroll
      for (int mi = 0; mi < MT; mi++)
        a[mi] = *(const bf16x8*)(&As[(wr*MT*16 + mi*16 + fm)*64] + p8);
      #pragma unroll
      for (int nj = 0; nj < NT; nj++)
        b[nj] = *(const bf16x8*)(&Ws[(wc*NT*16 + nj*16 + fm)*64] + p8);
      #pragma unroll
      for (int mi = 0; mi < MT; mi++)
        #pragma unroll
        for (int nj = 0; nj < NT; nj++)
          acc[mi][nj] = __builtin_amdgcn_mfma_f32_16x16x32_bf16(a[mi], b[nj], acc[mi][nj], 0, 0, 0);
    }
    __syncthreads();
  }
  // C/D layout: row = (lane>>4)*4 + r, col = lane&15  [verified m89/m91]
  int crow = (lane >> 4) * 4;
  int ccol = lane & 15;
  int segmask = (1 << segsh) - 1;
  #pragma unroll
  for (int mi = 0; mi < MT; mi++){
    #pragma unroll
    for (int nj = 0; nj < NT; nj++){
      int gm0 = bm*BM + wr*MT*16 + mi*16 + crow;
      int gn  = bn*BN + wc*NT*16 + nj*16 + ccol;
      int seg = gn >> segsh;
      const void* bb = (seg == 0) ? b0 : ((seg == 1) ? b1 : b2);
      float bv = loadIn(bb, boff + (gn & segmask), isbf);
      #pragma unroll
      for (int r = 0; r < 4; r++){
        int gm = gm0 + r;
        size_t idx = (size_t)gm * ldc + gn;
        float v = acc[mi][nj][r] + bv;
        if (relu) v = fmaxf(v, 0.f);
        if (resid) v += resid[idx];
        if (om) ((ushort_t*)out)[idx] = f2b(v);
        else    ((float*)out)[idx] = v;
        if (addout) addout[idx] += v;
      }
    }
  }
}

// om: 0 = fp32 out, 1 = bf16 out, 2 = input dtype (for d_out)
__global__ __launch_bounds__(256, 2) void gemm64(
    const int* __restrict__ flagp, const ushort_t* __restrict__ A,
    const ushort_t* __restrict__ W,
    const void* __restrict__ b0, const void* __restrict__ b1, const void* __restrict__ b2,
    size_t boff, int segsh,
    const float* resid, float* addout, void* out, int om, int ldc, int K, int relu)
{
  __shared__ __align__(16) ushort_t As[64*64];
  __shared__ __align__(16) ushort_t Ws[64*64];
  int isbf = *flagp;
  if (om == 2) om = isbf;
  gemm_core<2,2>(isbf, A, W, b0, b1, b2, boff, segsh, resid, addout, out, om, ldc, K, relu, As, Ws);
}

__global__ __launch_bounds__(256, 2) void gemm128(
    const int* __restrict__ flagp, const ushort_t* __restrict__ A,
    const ushort_t* __restrict__ W,
    const void* __restrict__ b0, const void* __restrict__ b1, const void* __restrict__ b2,
    size_t boff, int segsh,
    const float* resid, float* addout, void* out, int om, int ldc, int K, int relu)
{
  __shared__ __align__(16) ushort_t As[128*64];
  __shared__ __align__(16) ushort_t Ws[128*64];
  int isbf = *flagp;
  if (om == 2) om = isbf;
  gemm_core<4,4>(isbf, A, W, b0, b1, b2, boff, segsh, resid, addout, out, om, ldc, K, relu, As, Ws);
}

// ---------------- attention: 8 queries per block; Q/K/V strided (ld) ----------
__global__ __launch_bounds__(256) void attn_kernel(
    const float* __restrict__ Q, const float* __restrict__ K,
    const float* __restrict__ V, int ld, const int* __restrict__ ktok,
    ushort_t* __restrict__ ctx, int causal)
{
  __shared__ __align__(16) float sQ[8][64];
  __shared__ __align__(16) float sS[8][512];
  __shared__ __align__(16) float sAcc[4][8][64];
  __shared__ float sInv[8];
  int tid = threadIdx.x;
  int blk = blockIdx.x;
  int qg = blk & 63;
  int h  = (blk >> 6) & 7;
  int b  = blk >> 9;
  int q0 = qg * 8;

  #pragma unroll
  for (int i = 0; i < 2; i++){
    int qi = (tid >> 6) + i*4;
    int d  = tid & 63;
    sQ[qi][d] = Q[((size_t)(b*512 + q0 + qi))*ld + h*64 + d];
  }
  __syncthreads();

  float dots[8];
  #pragma unroll
  for (int i = 0; i < 2; i++){
    int k = tid + i*256;
    const float4* K4 = (const float4*)(K + ((size_t)(b*512 + k))*ld + h*64);
    #pragma unroll
    for (int qi = 0; qi < 8; qi++) dots[qi] = 0.f;
    #pragma unroll
    for (int d4 = 0; d4 < 16; d4++){
      float4 kv = K4[d4];
      #pragma unroll
      for (int qi = 0; qi < 8; qi++){
        float4 qv = ((const float4*)sQ)[qi*16 + d4];
        dots[qi] += kv.x*qv.x + kv.y*qv.y + kv.z*qv.z + kv.w*qv.w;
      }
    }
    int pad = (ktok[b*512 + k] == 0);
    #pragma unroll
    for (int qi = 0; qi < 8; qi++){
      bool m = pad || (causal && (k > q0 + qi));
      sS[qi][k] = m ? -1e9f : dots[qi]*0.125f;
    }
  }
  __syncthreads();

  {
    int wv = tid >> 6, ln = tid & 63;
    #pragma unroll
    for (int rr = 0; rr < 2; rr++){
      int r = wv*2 + rr;
      float vals[8];
      float m = -1e30f;
      #pragma unroll
      for (int j = 0; j < 8; j++){ vals[j] = sS[r][j*64 + ln]; m = fmaxf(m, vals[j]); }
      #pragma unroll
      for (int off = 1; off < 64; off <<= 1) m = fmaxf(m, __shfl_xor(m, off));
      float s = 0.f;
      #pragma unroll
      for (int j = 0; j < 8; j++){ vals[j] = __expf(vals[j] - m); s += vals[j]; }
      #pragma unroll
      for (int off = 1; off < 64; off <<= 1) s += __shfl_xor(s, off);
      #pragma unroll
      for (int j = 0; j < 8; j++) sS[r][j*64 + ln] = vals[j];
      if (ln == 0) sInv[r] = 1.f / s;
    }
  }
  __syncthreads();

  {
    int d = tid & 63, kc = tid >> 6;
    float acc[8];
    #pragma unroll
    for (int qi = 0; qi < 8; qi++) acc[qi] = 0.f;
    const float* Vp = V + ((size_t)(b*512 + kc*128))*ld + h*64 + d;
    for (int k4 = 0; k4 < 32; k4++){
      float v0 = Vp[(size_t)(k4*4+0)*ld];
      float v1 = Vp[(size_t)(k4*4+1)*ld];
      float v2 = Vp[(size_t)(k4*4+2)*ld];
      float v3 = Vp[(size_t)(k4*4+3)*ld];
      #pragma unroll
      for (int qi = 0; qi < 8; qi++){
        float4 p = ((const float4*)&sS[qi][kc*128])[k4];
        acc[qi] += p.x*v0 + p.y*v1 + p.z*v2 + p.w*v3;
      }
    }
    #pragma unroll
    for (int qi = 0; qi < 8; qi++) sAcc[kc][qi][d] = acc[qi];
  }
  __syncthreads();

  #pragma unroll
  for (int i = 0; i < 2; i++){
    int o = tid + i*256;
    int qi = o >> 6, d = o & 63;
    float v = (sAcc[0][qi][d] + sAcc[1][qi][d] + sAcc[2][qi][d] + sAcc[3][qi][d]) * sInv[qi];
    ctx[((size_t)(b*512 + q0 + qi))*DM + h*64 + d] = f2b(v);
  }
}

// ---------------- host ----------------
extern "C" void kernel_launch(void* const* d_in, const int* in_sizes, int n_in,
                              void* d_out, int out_size, void* d_ws, size_t ws_size,
                              hipStream_t stream)
{
  const int* enc_in = (const int*)d_in[0];
  const int* dec_in = (const int*)d_in[1];

  char* ws = (char*)d_ws;
  float*    xf   = (float*)(ws);                 // 0..4 MB   residual stream (fp32)
  float*    qkvf = (float*)(ws + (4u<<20));      // 4..17 MB  fused QKV [M,1536] fp32
  float*    caf  = (float*)(ws + (17u<<20));     // 17..21 MB cross-attn output
  ushort_t* hb   = (ushort_t*)(ws + (21u<<20));  // 2 MB  bf16 LN out
  ushort_t* ctxb = (ushort_t*)(ws + (23u<<20));  // 2 MB  bf16 attn ctx
  ushort_t* ffb  = (ushort_t*)(ws + (25u<<20));  // 8 MB  bf16 ffn hidden
  ushort_t* encb = (ushort_t*)(ws + (33u<<20));  // 2 MB  bf16 encoder out
  ushort_t* yb   = (ushort_t*)(ws + (35u<<20));  // 2 MB  bf16 final y
  int*      flagp= (int*)(ws + (37u<<20));       // dtype flag
  ushort_t* wA   = (ushort_t*)(ws + (40u<<20));  // bf16 weight arena (~77 MB)

  const size_t need = (40ull<<20) + 2ull*ARENA_ELEMS;
  if (ws_size < need) return;   // ws has been >=1GB on this harness; fail loudly if not

  detect_kernel<<<1, 64, 0, stream>>>((const unsigned*)d_in[4], flagp);

  conv12_kernel<<<4608, 256, 0, stream>>>(flagp, wA,
      d_in[5], d_in[7], d_in[9], d_in[11], d_in[13], d_in[15], d_in[17], d_in[19],
      d_in[21], d_in[23], d_in[25], d_in[27]);
  conv4_kernel<<<6144, 256, 0, stream>>>(flagp, wA, d_in[29], d_in[31], d_in[33], d_in[35]);
  conv1_kernel<<<8000, 256, 0, stream>>>(flagp, wA, d_in[49]);

  auto GEMM = [&](const void* A, size_t woff, int b0, int b1, int b2, size_t boff,
                  int segsh, const float* resid, float* addout, void* out, int om,
                  int N, int Kd, int relu, int ldc){
    gemm64<<<dim3(32, N/64), 256, 0, stream>>>(flagp, (const ushort_t*)A, wA + woff,
        d_in[b0], d_in[b1], d_in[b2], boff, segsh, resid, addout, out, om, ldc, Kd, relu);
  };
  auto LN = [&](const float* x, int gi, size_t go, int bi, size_t bo, ushort_t* o){
    ln_kernel<<<MROWS, 256, 0, stream>>>(flagp, x, d_in[gi], go, d_in[bi], bo, o);
  };
  float* Qp = qkvf;            // ld = 1536
  float* Kp = qkvf + 512;
  float* Vp = qkvf + 1024;

  // ======== encoder ========
  embed_kernel<<<MROWS, 256, 0, stream>>>(flagp, enc_in, d_in[2], d_in[4], xf);
  for (int l = 0; l < NLAYER; l++){
    size_t bo = (size_t)l*DM;
    LN(xf, 37, bo, 38, bo, hb);
    GEMM(hb, OFF_ENC_QKV + (size_t)l*3*LW, 6, 8, 10, bo, 9, nullptr, nullptr, qkvf, 0, 1536, DM, 0, 1536);
    attn_kernel<<<2048, 256, 0, stream>>>(Qp, Kp, Vp, 1536, enc_in, ctxb, 0);
    GEMM(ctxb, OFF_ENC_O + (size_t)l*LW, 12, 12, 12, bo, 15, xf, nullptr, xf, 0, 512, DM, 0, 512);
    LN(xf, 39, bo, 40, bo, hb);
    GEMM(hb,  OFF_EF1 + (size_t)l*LF, 30, 30, 30, (size_t)l*DFF_, 15, nullptr, nullptr, ffb, 1, DFF_, DM, 1, DFF_);
    GEMM(ffb, OFF_EF2 + (size_t)l*LF, 32, 32, 32, bo, 15, xf, nullptr, xf, 0, 512, DFF_, 0, 512);
  }
  LN(xf, 47, 0, 48, 0, encb);

  // ======== decoder ========
  embed_kernel<<<MROWS, 256, 0, stream>>>(flagp, dec_in, d_in[3], d_in[4], xf);
  for (int l = 0; l < NLAYER; l++){
    size_t bo = (size_t)l*DM;
    // self-attn (causal + dec pad)
    LN(xf, 41, bo, 42, bo, hb);
    GEMM(hb, OFF_DEC_QKV + (size_t)l*3*LW, 14, 16, 18, bo, 9, nullptr, nullptr, qkvf, 0, 1536, DM, 0, 1536);
    attn_kernel<<<2048, 256, 0, stream>>>(Qp, Kp, Vp, 1536, dec_in, ctxb, 1);
    GEMM(ctxb, OFF_DEC_O + (size_t)l*LW, 20, 20, 20, bo, 15, xf, nullptr, xf, 0, 512, DM, 0, 512);
    // cross-attn (enc pad, K/V from encoder output)
    LN(xf, 43, bo, 44, bo, hb);
    GEMM(hb,   OFF_DC_Q  + (size_t)l*LW,   22, 22, 22, bo, 15, nullptr, nullptr, Qp, 0, 512,  DM, 0, 1536);
    GEMM(encb, OFF_DC_KV + (size_t)l*2*LW, 24, 26, 26, bo, 9,  nullptr, nullptr, Kp, 0, 1024, DM, 0, 1536);
    attn_kernel<<<2048, 256, 0, stream>>>(Qp, Kp, Vp, 1536, enc_in, ctxb, 0);
    // caf = ctx@Wo + bo ; xf += caf (fused add)
    GEMM(ctxb, OFF_DC_O + (size_t)l*LW, 28, 28, 28, bo, 15, nullptr, xf, caf, 0, 512, DM, 0, 512);
    // ffn with residual = ca; last layer writes bf16 y directly
    LN(xf, 45, bo, 46, bo, hb);
    GEMM(hb, OFF_DF1 + (size_t)l*LF, 34, 34, 34, (size_t)l*DFF_, 15, nullptr, nullptr, ffb, 1, DFF_, DM, 1, DFF_);
    if (l == NLAYER-1)
      GEMM(ffb, OFF_DF2 + (size_t)l*LF, 36, 36, 36, bo, 15, caf, nullptr, yb, 1, 512, DFF_, 0, 512);
    else
      GEMM(ffb, OFF_DF2 + (size_t)l*LF, 36, 36, 36, bo, 15, caf, nullptr, xf, 0, 512, DFF_, 0, 512);
  }

  // ======== final projection (output in input dtype), 128^2 tiles ========
  gemm128<<<dim3(16, VOCAB/128), 256, 0, stream>>>(flagp, yb, wA + OFF_PROJ,
      d_in[50], d_in[50], d_in[50], 0, 15, nullptr, nullptr, d_out, 2, VOCAB, DM, 0);
}

// Round 4
// 1331.568 us; speedup vs baseline: 2.0438x; 2.0438x over previous
//
#include <hip/hip_runtime.h>
#include <string.h>

typedef unsigned short ushort_t;

#define NLAYER 3
#define MROWS 2048      // B*L = 4*512
#define DM 512
#define DFF_ 2048
#define VOCAB 32000

__device__ __forceinline__ float b2f(ushort_t u){
  union { unsigned int u; float f; } c; c.u = ((unsigned int)u) << 16; return c.f;
}
__device__ __forceinline__ ushort_t f2b(float f){
  union { float f; unsigned int u; } c; c.f = f;
  unsigned int u = c.u;
  u += 0x7FFFu + ((u >> 16) & 1u);   // RNE
  return (ushort_t)(u >> 16);
}

using bf16x8 = __attribute__((ext_vector_type(8))) short;
using f32x4  = __attribute__((ext_vector_type(4))) float;
using u16x4  = __attribute__((ext_vector_type(4))) ushort_t;

typedef const __attribute__((address_space(1))) unsigned int* gas1_t;
typedef __attribute__((address_space(3))) unsigned int* las3_t;
__device__ __forceinline__ void gload16(const void* g, void* l){
  // async global->LDS, 16B/lane; LDS dest = wave-uniform base + lane*16
  __builtin_amdgcn_global_load_lds((gas1_t)g, (las3_t)l, 16, 0, 0);
}

// ---------------- arena layout (elems, all bf16) ----------------
#define LW  262144ull     // 512*512
#define LF  1048576ull    // 2048*512
#define PROJ_T 16384000ull
#define OFF_ENC_QKV (0ull)
#define OFF_ENC_O   (9ull*LW)
#define OFF_DEC_QKV (12ull*LW)
#define OFF_DEC_O   (21ull*LW)
#define OFF_DC_Q    (24ull*LW)
#define OFF_DC_KV   (27ull*LW)
#define OFF_DC_O    (33ull*LW)
#define OFF_EF1     (36ull*LW)
#define OFF_EF2     (36ull*LW + 3ull*LF)
#define OFF_DF1     (36ull*LW + 6ull*LF)
#define OFF_DF2     (36ull*LW + 9ull*LF)
#define OFF_PROJ    (36ull*LW + 12ull*LF)
#define ARENA_ELEMS (36ull*LW + 12ull*LF + PROJ_T)

// ---------------- dtype detect: pe[0,0]=0.0, pe[0,1]=1.0 ----------------
__global__ void detect_kernel(const unsigned* __restrict__ pe, int* flag){
  if (threadIdx.x == 0) *flag = (pe[0] != 0u) ? 1 : 0;   // 1 = bf16 storage
}

__device__ __forceinline__ float loadIn(const void* p, size_t i, int isbf){
  return isbf ? b2f(((const ushort_t*)p)[i]) : ((const float*)p)[i];
}

// ---------------- embedding + positional encoding ----------------
__global__ __launch_bounds__(256) void embed_kernel(
    const int* __restrict__ flagp, const int* __restrict__ tok,
    const void* __restrict__ emb, const void* __restrict__ pe,
    float* __restrict__ out)
{
  int isbf = *flagp;
  int row = blockIdx.x, tid = threadIdx.x;
  int t = row & 511;
  int id = tok[row];
  const float scale = 22.62741699796952f;   // sqrt(512)
  #pragma unroll
  for (int i = 0; i < 2; i++){
    int d = tid + i*256;
    float e = loadIn(emb, (size_t)id*DM + d, isbf);
    float p = loadIn(pe,  (size_t)t*DM + d, isbf);
    out[(size_t)row*DM + d] = e * scale + p;
  }
}

// ---------------- layernorm: fp32 in -> bf16 out ----------------
__global__ __launch_bounds__(256) void ln_kernel(
    const int* __restrict__ flagp, const float* __restrict__ x,
    const void* __restrict__ g, size_t goff,
    const void* __restrict__ beta, size_t boff,
    ushort_t* __restrict__ out)
{
  int isbf = *flagp;
  __shared__ float red[8];
  int row = blockIdx.x, tid = threadIdx.x;
  const float* xr = x + (size_t)row*DM;
  float v0 = xr[tid], v1 = xr[tid+256];
  float s = v0 + v1;
  #pragma unroll
  for (int off = 1; off < 64; off <<= 1) s += __shfl_xor(s, off);
  if ((tid & 63) == 0) red[tid >> 6] = s;
  __syncthreads();
  float mean = (red[0]+red[1]+red[2]+red[3]) * (1.f/512.f);
  float d0 = v0 - mean, d1 = v1 - mean;
  float sq = d0*d0 + d1*d1;
  #pragma unroll
  for (int off = 1; off < 64; off <<= 1) sq += __shfl_xor(sq, off);
  if ((tid & 63) == 0) red[4 + (tid >> 6)] = sq;
  __syncthreads();
  float var = (red[4]+red[5]+red[6]+red[7]) * (1.f/512.f);
  float rs = rsqrtf(var + 1e-5f);
  float g0 = loadIn(g, goff + tid, isbf),     g1 = loadIn(g, goff + tid + 256, isbf);
  float b0 = loadIn(beta, boff + tid, isbf),  b1 = loadIn(beta, boff + tid + 256, isbf);
  out[(size_t)row*DM + tid]       = f2b(d0*rs*g0 + b0);
  out[(size_t)row*DM + tid + 256] = f2b(d1*rs*g1 + b1);
}

// ---------------- weight staging into bf16 arena (convert fp32 / copy bf16) ----
__device__ __forceinline__ void stage_chunk(int isbf, ushort_t* __restrict__ dst,
                                            const void* __restrict__ src,
                                            size_t soff, size_t doff, int tid)
{
  size_t so = soff + (size_t)tid*8;
  size_t dofs = doff + (size_t)tid*8;
  if (isbf){
    *(uint4*)(dst + dofs) = *(const uint4*)((const ushort_t*)src + so);
  } else {
    const float* s = (const float*)src;
    float4 a = *(const float4*)(s + so);
    float4 b = *(const float4*)(s + so + 4);
    union { ushort_t u[8]; uint4 v; } pk;
    pk.u[0]=f2b(a.x); pk.u[1]=f2b(a.y); pk.u[2]=f2b(a.z); pk.u[3]=f2b(a.w);
    pk.u[4]=f2b(b.x); pk.u[5]=f2b(b.y); pk.u[6]=f2b(b.z); pk.u[7]=f2b(b.w);
    *(uint4*)(dst + dofs) = pk.v;
  }
}

// 12 attention weight tensors [3,512,512] -> fused per-layer arena layout
__global__ __launch_bounds__(256) void conv12_kernel(const int* __restrict__ flagp,
    ushort_t* __restrict__ dst,
    const void* __restrict__ s0, const void* __restrict__ s1,
    const void* __restrict__ s2, const void* __restrict__ s3,
    const void* __restrict__ s4, const void* __restrict__ s5,
    const void* __restrict__ s6, const void* __restrict__ s7,
    const void* __restrict__ s8, const void* __restrict__ s9,
    const void* __restrict__ s10, const void* __restrict__ s11)
{
  int isbf = *flagp;
  int t  = blockIdx.x / 384;          // 12 tensors x (3 layers x 128 blocks)
  int lb = blockIdx.x - t*384;
  int l  = lb >> 7;
  int blk= lb & 127;
  const void* s = t==0?s0:t==1?s1:t==2?s2:t==3?s3:t==4?s4:t==5?s5:
                  t==6?s6:t==7?s7:t==8?s8:t==9?s9:t==10?s10:s11;
  size_t base, stride;
  switch(t){
    case 0:  base = OFF_ENC_QKV;        stride = 3*LW; break;  // eWq
    case 1:  base = OFF_ENC_QKV + LW;   stride = 3*LW; break;  // eWk
    case 2:  base = OFF_ENC_QKV + 2*LW; stride = 3*LW; break;  // eWv
    case 3:  base = OFF_ENC_O;          stride = LW;   break;  // eWo
    case 4:  base = OFF_DEC_QKV;        stride = 3*LW; break;  // dsWq
    case 5:  base = OFF_DEC_QKV + LW;   stride = 3*LW; break;  // dsWk
    case 6:  base = OFF_DEC_QKV + 2*LW; stride = 3*LW; break;  // dsWv
    case 7:  base = OFF_DEC_O;          stride = LW;   break;  // dsWo
    case 8:  base = OFF_DC_Q;           stride = LW;   break;  // dcWq
    case 9:  base = OFF_DC_KV;          stride = 2*LW; break;  // dcWk
    case 10: base = OFF_DC_KV + LW;     stride = 2*LW; break;  // dcWv
    default: base = OFF_DC_O;           stride = LW;   break;  // dcWo
  }
  stage_chunk(isbf, dst, s, (size_t)l*LW + (size_t)blk*2048,
              base + (size_t)l*stride + (size_t)blk*2048, threadIdx.x);
}

// 4 FFN weight tensors [3,*,*] -> arena
__global__ __launch_bounds__(256) void conv4_kernel(const int* __restrict__ flagp,
    ushort_t* __restrict__ dst,
    const void* __restrict__ s0, const void* __restrict__ s1,
    const void* __restrict__ s2, const void* __restrict__ s3)
{
  int isbf = *flagp;
  int t  = blockIdx.x / 1536;
  int lb = blockIdx.x - t*1536;
  int l  = lb >> 9;
  int blk= lb & 511;
  const void* s = t==0?s0:t==1?s1:t==2?s2:s3;
  size_t base = t==0?OFF_EF1 : t==1?OFF_EF2 : t==2?OFF_DF1 : OFF_DF2;
  stage_chunk(isbf, dst, s, (size_t)l*LF + (size_t)blk*2048,
              base + (size_t)l*LF + (size_t)blk*2048, threadIdx.x);
}

// projW 32000*512 (8000 blocks)
__global__ __launch_bounds__(256) void conv1_kernel(const int* __restrict__ flagp,
    ushort_t* __restrict__ dst, const void* __restrict__ src)
{
  int isbf = *flagp;
  stage_chunk(isbf, dst, src, (size_t)blockIdx.x*2048,
              OFF_PROJ + (size_t)blockIdx.x*2048, threadIdx.x);
}

// ---------------- GEMM: C[M,N] = A[M,K](bf16) @ W[N,K]^T(arena bf16) + bias ----
// vt: if non-null, columns gn >= vtseg are written TRANSPOSED bf16 to vt[gn-vtseg][gm]
// (ld 2048) instead of the normal output (used to produce V^T for MFMA attention).
template<int MT, int NT>
__device__ __forceinline__ void gemm_core(
    int isbf, const ushort_t* __restrict__ A, const ushort_t* __restrict__ W,
    const void* __restrict__ b0, const void* __restrict__ b1, const void* __restrict__ b2,
    size_t boff, int segsh,
    const float* __restrict__ resid, float* __restrict__ addout,
    void* __restrict__ out, int om, int ldc, int K, int relu,
    ushort_t* __restrict__ vt, int vtseg,
    ushort_t* As, ushort_t* Ws)
{
  constexpr int BM = MT*32, BN = NT*32;
  int tid = threadIdx.x;
  int flat = blockIdx.y * gridDim.x + blockIdx.x;
  int nwg  = gridDim.x * gridDim.y;
  int swz = flat;
  if ((nwg & 7) == 0){ int cpx = nwg >> 3; swz = (flat & 7) * cpx + (flat >> 3); }
  int bm = swz % (int)gridDim.x;
  int bn = swz / (int)gridDim.x;

  int wave = tid >> 6, lane = tid & 63;
  int wr = wave >> 1, wc = wave & 1;
  f32x4 acc[MT][NT];
  #pragma unroll
  for (int i=0;i<MT;i++)
    #pragma unroll
    for (int j=0;j<NT;j++) acc[i][j] = (f32x4){0.f,0.f,0.f,0.f};

  // physical col-slot p of row r holds logical 16B-slot s = p ^ (r&7)
  int srow = tid >> 3;
  int scol = (((tid & 7) ^ (srow & 7)) * 8);
  const ushort_t* Ag = A + (size_t)(bm*BM + srow)*K + scol;
  const ushort_t* Wg = W + (size_t)(bn*BN + srow)*K + scol;
  ushort_t* ldsA = As + wave*512;
  ushort_t* ldsW = Ws + wave*512;

  int fm = lane & 15;
  int xa = fm & 7;

  for (int k0 = 0; k0 < K; k0 += 64){
    #pragma unroll
    for (int j = 0; j < MT; j++)
      gload16(Ag + (size_t)(j*32)*K + k0, ldsA + j*2048);
    #pragma unroll
    for (int j = 0; j < NT; j++)
      gload16(Wg + (size_t)(j*32)*K + k0, ldsW + j*2048);
    __syncthreads();
    #pragma unroll
    for (int kk = 0; kk < 2; kk++){
      int p8 = (((lane >> 4) + kk*4) ^ xa) * 8;
      bf16x8 a[MT], b[NT];
      #pragma unroll
      for (int mi = 0; mi < MT; mi++)
        a[mi] = *(const bf16x8*)(&As[(wr*MT*16 + mi*16 + fm)*64] + p8);
      #pragma unroll
      for (int nj = 0; nj < NT; nj++)
        b[nj] = *(const bf16x8*)(&Ws[(wc*NT*16 + nj*16 + fm)*64] + p8);
      #pragma unroll
      for (int mi = 0; mi < MT; mi++)
        #pragma unroll
        for (int nj = 0; nj < NT; nj++)
          acc[mi][nj] = __builtin_amdgcn_mfma_f32_16x16x32_bf16(a[mi], b[nj], acc[mi][nj], 0, 0, 0);
    }
    __syncthreads();
  }
  // C/D layout: row = (lane>>4)*4 + r, col = lane&15  [verified m89/m91]
  int crow = (lane >> 4) * 4;
  int ccol = lane & 15;
  int segmask = (1 << segsh) - 1;
  #pragma unroll
  for (int mi = 0; mi < MT; mi++){
    #pragma unroll
    for (int nj = 0; nj < NT; nj++){
      int gm0 = bm*BM + wr*MT*16 + mi*16 + crow;
      int gn  = bn*BN + wc*NT*16 + nj*16 + ccol;
      int seg = gn >> segsh;
      const void* bb = (seg == 0) ? b0 : ((seg == 1) ? b1 : b2);
      float bv = loadIn(bb, boff + (gn & segmask), isbf);
      if (vt && gn >= vtseg){
        u16x4 pk;
        #pragma unroll
        for (int r = 0; r < 4; r++) pk[r] = f2b(acc[mi][nj][r] + bv);
        *(u16x4*)(vt + (size_t)(gn - vtseg)*2048 + gm0) = pk;   // 8B aligned (gm0%4==0)
      } else {
        #pragma unroll
        for (int r = 0; r < 4; r++){
          int gm = gm0 + r;
          size_t idx = (size_t)gm * ldc + gn;
          float v = acc[mi][nj][r] + bv;
          if (relu) v = fmaxf(v, 0.f);
          if (resid) v += resid[idx];
          if (om) ((ushort_t*)out)[idx] = f2b(v);
          else    ((float*)out)[idx] = v;
          if (addout) addout[idx] += v;
        }
      }
    }
  }
}

// om: 0 = fp32 out, 1 = bf16 out, 2 = input dtype (for d_out)
__global__ __launch_bounds__(256, 2) void gemm64(
    const int* __restrict__ flagp, const ushort_t* __restrict__ A,
    const ushort_t* __restrict__ W,
    const void* __restrict__ b0, const void* __restrict__ b1, const void* __restrict__ b2,
    size_t boff, int segsh,
    const float* resid, float* addout, void* out, int om, int ldc, int K, int relu,
    ushort_t* vt, int vtseg)
{
  __shared__ __align__(16) ushort_t As[64*64];
  __shared__ __align__(16) ushort_t Ws[64*64];
  int isbf = *flagp;
  if (om == 2) om = isbf;
  gemm_core<2,2>(isbf, A, W, b0, b1, b2, boff, segsh, resid, addout, out, om, ldc, K, relu, vt, vtseg, As, Ws);
}

__global__ __launch_bounds__(256, 2) void gemm128(
    const int* __restrict__ flagp, const ushort_t* __restrict__ A,
    const ushort_t* __restrict__ W,
    const void* __restrict__ b0, const void* __restrict__ b1, const void* __restrict__ b2,
    size_t boff, int segsh,
    const float* resid, float* addout, void* out, int om, int ldc, int K, int relu,
    ushort_t* vt, int vtseg)
{
  __shared__ __align__(16) ushort_t As[128*64];
  __shared__ __align__(16) ushort_t Ws[128*64];
  int isbf = *flagp;
  if (om == 2) om = isbf;
  gemm_core<4,4>(isbf, A, W, b0, b1, b2, boff, segsh, resid, addout, out, om, ldc, K, relu, vt, vtseg, As, Ws);
}

// ---------------- MFMA attention ----------------
// Inputs bf16: Qb rows [b*512+q][1024] (cols h*64..), Kb same (already offset +512 by host),
// Vt [512 d_model][2048 tokens]. Per block: one (b,h), 64 q rows; 4 waves x 16 q rows.
// Online softmax over 64-k tiles; P via wave-private swizzled LDS bounce.
__global__ __launch_bounds__(256) void attn_mfma(
    const ushort_t* __restrict__ Qb, const ushort_t* __restrict__ Kb,
    const ushort_t* __restrict__ Vt, const int* __restrict__ ktok,
    ushort_t* __restrict__ ctxo, int causal)
{
  __shared__ __align__(16) ushort_t sQ[64*64];
  __shared__ __align__(16) ushort_t sK[64*64];
  __shared__ __align__(16) ushort_t sV[64*64];
  __shared__ __align__(16) ushort_t sP[64*64];   // 4 waves x [16 q][64 k]
  __shared__ float sMask[64];
  int tid = threadIdx.x, wave = tid >> 6, lane = tid & 63;
  int fm = lane & 15, fg = lane >> 4;
  int blk = blockIdx.x;                 // 256 = qt(8) + h(8)*8 + b(4)*64
  int qt = blk & 7, h = (blk >> 3) & 7, b = blk >> 6;
  int qb0 = qt * 64;

  int srow = tid >> 3;
  int scol = ((tid & 7) ^ (srow & 7)) * 8;
  const ushort_t* Qg = Qb + (size_t)(b*512 + qb0 + srow)*1024 + h*64 + scol;
  const ushort_t* Kg = Kb + (size_t)(b*512 + srow)*1024 + h*64 + scol;
  const ushort_t* Vg = Vt + (size_t)(h*64 + srow)*2048 + b*512 + scol;

  // stage Q once (barrier folded into first tile's)
  gload16(Qg,                   sQ + wave*512);
  gload16(Qg + (size_t)32*1024, sQ + 2048 + wave*512);

  f32x4 ctx[4];
  #pragma unroll
  for (int i = 0; i < 4; i++) ctx[i] = (f32x4){0.f,0.f,0.f,0.f};
  float m[4] = {-1e30f,-1e30f,-1e30f,-1e30f};
  float l[4] = {0.f,0.f,0.f,0.f};

  int nkt = causal ? (qt + 1) : 8;
  for (int kt = 0; kt < nkt; kt++){
    int k0 = kt * 64;
    gload16(Kg + (size_t)k0*1024,        sK + wave*512);
    gload16(Kg + (size_t)(k0+32)*1024,   sK + 2048 + wave*512);
    gload16(Vg + k0,                     sV + wave*512);
    gload16(Vg + (size_t)32*2048 + k0,   sV + 2048 + wave*512);
    if (tid < 64) sMask[tid] = (ktok[b*512 + k0 + tid] == 0) ? -1e9f : 0.f;
    __syncthreads();

    // S[16q x 64k] per wave = Q_tile @ K_tile^T
    f32x4 s[4];
    #pragma unroll
    for (int nt = 0; nt < 4; nt++) s[nt] = (f32x4){0.f,0.f,0.f,0.f};
    #pragma unroll
    for (int kk = 0; kk < 2; kk++){
      int p8 = ((fg + kk*4) ^ (fm & 7)) * 8;
      bf16x8 aq = *(const bf16x8*)(&sQ[(wave*16 + fm)*64] + p8);
      #pragma unroll
      for (int nt = 0; nt < 4; nt++){
        bf16x8 bk = *(const bf16x8*)(&sK[(nt*16 + fm)*64] + p8);
        s[nt] = __builtin_amdgcn_mfma_f32_16x16x32_bf16(aq, bk, s[nt], 0, 0, 0);
      }
    }
    // scale + pad mask + causal (diagonal tile only)
    #pragma unroll
    for (int nt = 0; nt < 4; nt++){
      float kb = sMask[nt*16 + fm];
      #pragma unroll
      for (int r = 0; r < 4; r++){
        float v = s[nt][r] * 0.125f + kb;
        if (causal && kt == qt){
          int kg = k0 + nt*16 + fm;
          int qg = qb0 + wave*16 + fg*4 + r;
          if (kg > qg) v = -1e9f;
        }
        s[nt][r] = v;
      }
    }
    // online softmax per q-row (row spread over the 16-lane fm group)
    #pragma unroll
    for (int r = 0; r < 4; r++){
      float tmax = fmaxf(fmaxf(s[0][r], s[1][r]), fmaxf(s[2][r], s[3][r]));
      #pragma unroll
      for (int off = 1; off < 16; off <<= 1) tmax = fmaxf(tmax, __shfl_xor(tmax, off));
      float mn = fmaxf(m[r], tmax);
      float sc = __expf(m[r] - mn);
      m[r] = mn;
      float rs = 0.f;
      #pragma unroll
      for (int nt = 0; nt < 4; nt++){
        float p = __expf(s[nt][r] - mn);
        s[nt][r] = p;
        rs += p;
      }
      #pragma unroll
      for (int off = 1; off < 16; off <<= 1) rs += __shfl_xor(rs, off);
      l[r] = l[r]*sc + rs;
      #pragma unroll
      for (int dt = 0; dt < 4; dt++) ctx[dt][r] *= sc;
    }
    // P -> bf16 into wave-private swizzled LDS [16 q][64 k]
    #pragma unroll
    for (int nt = 0; nt < 4; nt++){
      int k = nt*16 + fm;
      int slot = k >> 3, kb7 = k & 7;
      #pragma unroll
      for (int r = 0; r < 4; r++){
        int q = fg*4 + r;
        sP[wave*1024 + q*64 + ((slot ^ (q & 7))*8) + kb7] = f2b(s[nt][r]);
      }
    }
    // ctx += P @ V_tile  (V^T staged: sV rows = d)
    #pragma unroll
    for (int kk = 0; kk < 2; kk++){
      int p8 = ((fg + kk*4) ^ (fm & 7)) * 8;
      bf16x8 ap = *(const bf16x8*)(&sP[wave*1024 + fm*64] + p8);
      #pragma unroll
      for (int dt = 0; dt < 4; dt++){
        bf16x8 bv = *(const bf16x8*)(&sV[(dt*16 + fm)*64] + p8);
        ctx[dt] = __builtin_amdgcn_mfma_f32_16x16x32_bf16(ap, bv, ctx[dt], 0, 0, 0);
      }
    }
    __syncthreads();
  }
  // epilogue: ctx/l -> bf16 ctx buffer [token][512]
  #pragma unroll
  for (int r = 0; r < 4; r++){
    float inv = 1.f / l[r];
    size_t q = (size_t)(b*512 + qb0 + wave*16 + fg*4 + r);
    #pragma unroll
    for (int dt = 0; dt < 4; dt++)
      ctxo[q*512 + h*64 + dt*16 + fm] = f2b(ctx[dt][r] * inv);
  }
}

// ---------------- host ----------------
extern "C" void kernel_launch(void* const* d_in, const int* in_sizes, int n_in,
                              void* d_out, int out_size, void* d_ws, size_t ws_size,
                              hipStream_t stream)
{
  const int* enc_in = (const int*)d_in[0];
  const int* dec_in = (const int*)d_in[1];

  char* ws = (char*)d_ws;
  float*    xf   = (float*)(ws);                 // 0..4 MB   residual (fp32)
  ushort_t* qkb  = (ushort_t*)(ws + (4u<<20));   // 4..8 MB   bf16 [2048][1024]: Q | K
  ushort_t* vtb  = (ushort_t*)(ws + (8u<<20));   // 8..10 MB  bf16 V^T [512][2048]
  float*    caf  = (float*)(ws + (10u<<20));     // 10..14 MB cross-attn out (fp32)
  ushort_t* hb   = (ushort_t*)(ws + (14u<<20));  // 2 MB  bf16 LN out
  ushort_t* ctxb = (ushort_t*)(ws + (16u<<20));  // 2 MB  bf16 attn ctx
  ushort_t* ffb  = (ushort_t*)(ws + (18u<<20));  // 8 MB  bf16 ffn hidden
  ushort_t* encb = (ushort_t*)(ws + (26u<<20));  // 2 MB  bf16 encoder out
  ushort_t* yb   = (ushort_t*)(ws + (28u<<20));  // 2 MB  bf16 final y
  int*      flagp= (int*)(ws + (30u<<20));       // dtype flag
  ushort_t* wA   = (ushort_t*)(ws + (40u<<20));  // bf16 weight arena (~77 MB)

  const size_t need = (40ull<<20) + 2ull*ARENA_ELEMS;
  if (ws_size < need) return;

  detect_kernel<<<1, 64, 0, stream>>>((const unsigned*)d_in[4], flagp);

  conv12_kernel<<<4608, 256, 0, stream>>>(flagp, wA,
      d_in[5], d_in[7], d_in[9], d_in[11], d_in[13], d_in[15], d_in[17], d_in[19],
      d_in[21], d_in[23], d_in[25], d_in[27]);
  conv4_kernel<<<6144, 256, 0, stream>>>(flagp, wA, d_in[29], d_in[31], d_in[33], d_in[35]);
  conv1_kernel<<<8000, 256, 0, stream>>>(flagp, wA, d_in[49]);

  auto GEMM = [&](const void* A, size_t woff, int b0, int b1, int b2, size_t boff,
                  int segsh, const float* resid, float* addout, void* out, int om,
                  int N, int Kd, int relu, int ldc, ushort_t* vt, int vtseg){
    gemm64<<<dim3(32, N/64), 256, 0, stream>>>(flagp, (const ushort_t*)A, wA + woff,
        d_in[b0], d_in[b1], d_in[b2], boff, segsh, resid, addout, out, om, ldc, Kd, relu, vt, vtseg);
  };
  auto LN = [&](const float* x, int gi, size_t go, int bi, size_t bo, ushort_t* o){
    ln_kernel<<<MROWS, 256, 0, stream>>>(flagp, x, d_in[gi], go, d_in[bi], bo, o);
  };
  auto ATTN = [&](const int* tok, int causal){
    attn_mfma<<<256, 256, 0, stream>>>(qkb, qkb + 512, vtb, tok, ctxb, causal);
  };

  // ======== encoder ========
  embed_kernel<<<MROWS, 256, 0, stream>>>(flagp, enc_in, d_in[2], d_in[4], xf);
  for (int l = 0; l < NLAYER; l++){
    size_t bo = (size_t)l*DM;
    LN(xf, 37, bo, 38, bo, hb);
    GEMM(hb, OFF_ENC_QKV + (size_t)l*3*LW, 6, 8, 10, bo, 9, nullptr, nullptr,
         qkb, 1, 1536, DM, 0, 1024, vtb, 1024);
    ATTN(enc_in, 0);
    GEMM(ctxb, OFF_ENC_O + (size_t)l*LW, 12, 12, 12, bo, 15, xf, nullptr, xf, 0, 512, DM, 0, 512, nullptr, 0);
    LN(xf, 39, bo, 40, bo, hb);
    GEMM(hb,  OFF_EF1 + (size_t)l*LF, 30, 30, 30, (size_t)l*DFF_, 15, nullptr, nullptr, ffb, 1, DFF_, DM, 1, DFF_, nullptr, 0);
    GEMM(ffb, OFF_EF2 + (size_t)l*LF, 32, 32, 32, bo, 15, xf, nullptr, xf, 0, 512, DFF_, 0, 512, nullptr, 0);
  }
  LN(xf, 47, 0, 48, 0, encb);

  // ======== decoder ========
  embed_kernel<<<MROWS, 256, 0, stream>>>(flagp, dec_in, d_in[3], d_in[4], xf);
  for (int l = 0; l < NLAYER; l++){
    size_t bo = (size_t)l*DM;
    // self-attn (causal + dec pad)
    LN(xf, 41, bo, 42, bo, hb);
    GEMM(hb, OFF_DEC_QKV + (size_t)l*3*LW, 14, 16, 18, bo, 9, nullptr, nullptr,
         qkb, 1, 1536, DM, 0, 1024, vtb, 1024);
    ATTN(dec_in, 1);
    GEMM(ctxb, OFF_DEC_O + (size_t)l*LW, 20, 20, 20, bo, 15, xf, nullptr, xf, 0, 512, DM, 0, 512, nullptr, 0);
    // cross-attn (enc pad, K/V from encoder output)
    LN(xf, 43, bo, 44, bo, hb);
    GEMM(hb,   OFF_DC_Q  + (size_t)l*LW,   22, 22, 22, bo, 15, nullptr, nullptr,
         qkb, 1, 512, DM, 0, 1024, nullptr, 0);
    GEMM(encb, OFF_DC_KV + (size_t)l*2*LW, 24, 26, 26, bo, 9,  nullptr, nullptr,
         qkb + 512, 1, 1024, DM, 0, 1024, vtb, 512);
    ATTN(enc_in, 0);
    // caf = ctx@Wo + bo ; xf += caf (fused add)
    GEMM(ctxb, OFF_DC_O + (size_t)l*LW, 28, 28, 28, bo, 15, nullptr, xf, caf, 0, 512, DM, 0, 512, nullptr, 0);
    // ffn with residual = ca; last layer writes bf16 y directly
    LN(xf, 45, bo, 46, bo, hb);
    GEMM(hb, OFF_DF1 + (size_t)l*LF, 34, 34, 34, (size_t)l*DFF_, 15, nullptr, nullptr, ffb, 1, DFF_, DM, 1, DFF_, nullptr, 0);
    if (l == NLAYER-1)
      GEMM(ffb, OFF_DF2 + (size_t)l*LF, 36, 36, 36, bo, 15, caf, nullptr, yb, 1, 512, DFF_, 0, 512, nullptr, 0);
    else
      GEMM(ffb, OFF_DF2 + (size_t)l*LF, 36, 36, 36, bo, 15, caf, nullptr, xf, 0, 512, DFF_, 0, 512, nullptr, 0);
  }

  // ======== final projection (output in input dtype), 128^2 tiles ========
  gemm128<<<dim3(16, VOCAB/128), 256, 0, stream>>>(flagp, yb, wA + OFF_PROJ,
      d_in[50], d_in[50], d_in[50], 0, 15, nullptr, nullptr, d_out, 2, VOCAB, DM, 0, nullptr, 0);
}